// Round 11
// baseline (334.577 us; speedup 1.0000x reference)
//
#include <hip/hip_runtime.h>
#include <hip/hip_bf16.h>

typedef _Float16 f16x8 __attribute__((ext_vector_type(8)));
typedef _Float16 f16x4 __attribute__((ext_vector_type(4)));
typedef float f32x4 __attribute__((ext_vector_type(4)));
typedef int i32x4 __attribute__((ext_vector_type(4)));

__device__ __forceinline__ float bf2f(unsigned short u) {
  union { unsigned int i; float f; } x; x.i = ((unsigned int)u) << 16; return x.f;
}
// clamp-to-finite fp16 convert: any upstream bug shows finite, not NaN
__device__ __forceinline__ _Float16 h16(float f) {
  return (_Float16)fminf(fmaxf(f, -60000.f), 60000.f);
}

// accurate -log(u): series for u near 1 (1-u exact by Sterbenz there)
__device__ __forceinline__ float neglog(float u) {
  if (u > 0.99f) {
    const float d = 1.0f - u;
    return d + 0.5f * d * d + (1.0f / 3.0f) * d * d * d;
  }
  return -__logf(u);
}

// plain butterfly sum across 64 lanes
__device__ __forceinline__ float wsum(float v) {
#pragma unroll
  for (int off = 1; off < 64; off <<= 1) v += __shfl_xor(v, off, 64);
  return v;
}

// St row-keyed XOR swizzle: element idx ^ ((row&7)<<3) (byte bits 4-6).
__device__ __forceinline__ int sidx(int row, int col) {
  return ((row) * 1024 + (col)) ^ (((row) & 7) << 3);
}

// Per-wave dtype detection. 0 = bf16 inputs, 1 = fp32 inputs.
__device__ __forceinline__ int wave_flag(const unsigned short* __restrict__ g, int tid) {
  const float f = bf2f(g[(tid & 63) * 2]);
  const unsigned long long m = __ballot((f >= 8e-7f) && (f <= 1.0f));
  return (m == ~0ull) ? 0 : 1;
}

// ---------------------------------------------------------------------------
// Kernel 0: convert hidden + Wq/Wk/Wv to fp16 once. Grid-stride, 1280 blocks.
// ---------------------------------------------------------------------------
__global__ __launch_bounds__(256) void cvt_inputs(
    const void* __restrict__ h, const void* __restrict__ wq,
    const void* __restrict__ wk, const void* __restrict__ wv,
    const unsigned short* __restrict__ gum, _Float16* __restrict__ dst)
{
  const int flg = wave_flag(gum, threadIdx.x);
  for (int c = blockIdx.x * 256 + threadIdx.x; c < 1310720; c += 1280 * 256) {
    const int c4 = c * 4;
    const void* src;
    int si;
    if (c4 < 2097152) { src = h; si = c4; }
    else {
      const int w = (c4 - 2097152) >> 20;        // 0,1,2
      si = (c4 - 2097152) & 1048575;
      src = (w == 0) ? wq : (w == 1) ? wk : wv;
    }
    f16x4 o;
    if (flg) {
      f32x4 v = __builtin_nontemporal_load((const f32x4*)((const float*)src + si));
#pragma unroll
      for (int j = 0; j < 4; j++) o[j] = h16(v[j]);
    } else {
      unsigned long long q = __builtin_nontemporal_load(
          (const unsigned long long*)((const unsigned short*)src + si));
      union { unsigned long long q; unsigned short u[4]; } ld; ld.q = q;
#pragma unroll
      for (int j = 0; j < 4; j++) o[j] = h16(bf2f(ld.u[j]));
    }
    *(f16x4*)(dst + c4) = o;
  }
}

// ---------------------------------------------------------------------------
// Kernel 1: QKV projection. 128x128 tile, 8 waves / 512 thr, BK=64,
// reg-staged double buffer. Unchanged from R8.
// ---------------------------------------------------------------------------
__global__ __launch_bounds__(512, 4) void qkv_gemm(
    const _Float16* __restrict__ cvt,   // [hid | Wq | Wk | Wv]
    const unsigned short* __restrict__ bq, const unsigned short* __restrict__ bk,
    const unsigned short* __restrict__ bv,
    const unsigned short* __restrict__ gum,
    _Float16* __restrict__ q_ws, _Float16* __restrict__ k_ws,
    _Float16* __restrict__ v_ws)
{
  __shared__ _Float16 At[128][72];  // 128 x 64 fp16, +8 pad
  __shared__ _Float16 Bt[128][72];
  const int flg = wave_flag(gum, threadIdx.x);
  const int tn = blockIdx.x;        // 16 M-tiles of 128 rows
  const int to = blockIdx.y;        // 24 N-tiles of 128 cols over [q|k|v]
  const int mat = to >> 3;          // 0=q 1=k 2=v
  const int o0 = (to & 7) * 128;
  const _Float16* hid16 = cvt;
  const _Float16* W16 = cvt + (size_t)(2 * 1024 * 1024) + (size_t)mat * 1024 * 1024;
  const unsigned short* bias = (mat == 0) ? bq : (mat == 1) ? bk : bv;
  const float* biasf = (const float*)bias;
  const int tid = threadIdx.x;
  const int lane = tid & 63, wave = tid >> 6;
  const int wm = (wave >> 2) * 64, wn = (wave & 3) * 32;  // 2M x 4N wave grid
  const int lm = lane & 15, lq = lane >> 4;
  f32x4 acc[4][2] = {};

  // staging: A and B each 128 rows x 8 chunks of 16B = 1024 chunks; 2/thread
  const int r0s = tid >> 3, cs = tid & 7;          // rows r0s, r0s+64
  i32x4 rA[2], rB[2];
  auto ldglobal = [&](int kc) {
#pragma unroll
    for (int i = 0; i < 2; i++)
      rA[i] = *(const i32x4*)(hid16 + (size_t)(tn * 128 + r0s + i * 64) * 1024 + kc + cs * 8);
#pragma unroll
    for (int i = 0; i < 2; i++)
      rB[i] = *(const i32x4*)(W16 + (size_t)(o0 + r0s + i * 64) * 1024 + kc + cs * 8);
  };

  ldglobal(0);
  for (int kc = 0; kc < 1024; kc += 64) {
    __syncthreads();   // previous chunk's frag reads complete
#pragma unroll
    for (int i = 0; i < 2; i++)
      *(i32x4*)(&At[r0s + i * 64][cs * 8]) = rA[i];
#pragma unroll
    for (int i = 0; i < 2; i++)
      *(i32x4*)(&Bt[r0s + i * 64][cs * 8]) = rB[i];
    __syncthreads();
    if (kc < 960) ldglobal(kc + 64);   // overlap next loads with MFMAs below

    f16x8 bfr[2][2];
#pragma unroll
    for (int nt = 0; nt < 2; nt++)
#pragma unroll
      for (int k2 = 0; k2 < 2; k2++)
        bfr[nt][k2] = *(const f16x8*)(&Bt[wn + nt * 16 + lm][k2 * 32 + lq * 8]);
#pragma unroll
    for (int mt = 0; mt < 4; mt++) {
      const f16x8 a0 = *(const f16x8*)(&At[wm + mt * 16 + lm][lq * 8]);
      const f16x8 a1 = *(const f16x8*)(&At[wm + mt * 16 + lm][32 + lq * 8]);
#pragma unroll
      for (int nt = 0; nt < 2; nt++) {
        acc[mt][nt] = __builtin_amdgcn_mfma_f32_16x16x32_f16(a0, bfr[nt][0], acc[mt][nt], 0, 0, 0);
        acc[mt][nt] = __builtin_amdgcn_mfma_f32_16x16x32_f16(a1, bfr[nt][1], acc[mt][nt], 0, 0, 0);
      }
    }
  }

  // epilogue: C/D layout col=lane&15, row=quad*4+reg
  _Float16* dst = (mat == 0) ? q_ws : (mat == 1) ? k_ws : v_ws;
#pragma unroll
  for (int nt = 0; nt < 2; nt++) {
    const int ol = o0 + wn + nt * 16 + lm;
    const float bias_v = flg ? biasf[ol] : bf2f(bias[ol]);
    const int hh = ol >> 6, dd = ol & 63;
#pragma unroll
    for (int mt = 0; mt < 4; mt++) {
#pragma unroll
      for (int rg = 0; rg < 4; rg++) {
        const int n = tn * 128 + wm + mt * 16 + lq * 4 + rg;  // b*1024+s
        const int b = n >> 10, s = n & 1023;
        dst[((size_t)(b * 16 + hh) * 1024 + s) * 64 + dd] = h16(acc[mt][nt][rg] + bias_v);
      }
    }
  }
}

// ---------------------------------------------------------------------------
// Kernel 2: transpose v [bh][s][64] -> vT [bh][64][s] via LDS 64x64 tiles,
// plus (grid y==32) dist_emb -> fp16 conversion.
// ---------------------------------------------------------------------------
__global__ __launch_bounds__(256) void transpose_v_emb(
    const _Float16* __restrict__ v_ws, _Float16* __restrict__ vT_ws,
    const void* __restrict__ de, const unsigned short* __restrict__ gum,
    _Float16* __restrict__ e16)
{
  __shared__ unsigned short Tt[64 * 66];
  const int tid = threadIdx.x;

  if (blockIdx.y == 32) {
    // dist_emb conversion: 2047*64 = 131008 halves = 32752 vec4 chunks
    const int flg = wave_flag(gum, tid);
    for (int c = blockIdx.x * 256 + tid; c < 32752; c += 16 * 256) {
      const int idx = c * 4;
      f16x4 o;
      if (flg) {
        f32x4 v = *(const f32x4*)((const float*)de + idx);
#pragma unroll
        for (int j = 0; j < 4; j++) o[j] = h16(v[j]);
      } else {
        union { unsigned long long q; unsigned short u[4]; } ld;
        ld.q = *(const unsigned long long*)((const unsigned short*)de + idx);
#pragma unroll
        for (int j = 0; j < 4; j++) o[j] = h16(bf2f(ld.u[j]));
      }
      *(f16x4*)(e16 + idx) = o;
    }
    return;
  }

  const int st = blockIdx.x;   // 16 s-tiles
  const int bh = blockIdx.y;   // 32
  const unsigned short* src = (const unsigned short*)(v_ws + (size_t)bh * 65536);
#pragma unroll
  for (int i = 0; i < 2; i++) {
    const int cid = i * 256 + tid;
    const int r = cid >> 3, c8 = cid & 7;   // row in tile, 8-half chunk
    union { i32x4 v; unsigned int w[4]; } ld;
    ld.v = *(const i32x4*)(src + (size_t)(st * 64 + r) * 64 + c8 * 8);
#pragma unroll
    for (int w = 0; w < 4; w++)
      *(unsigned int*)(&Tt[r * 66 + c8 * 8 + w * 2]) = ld.w[w];
  }
  __syncthreads();
  const int d = tid >> 2, sc = (tid & 3) * 16;
  unsigned short us[16];
#pragma unroll
  for (int j = 0; j < 16; j++) us[j] = Tt[(sc + j) * 66 + d];
  unsigned short* dst = (unsigned short*)(vT_ws + (size_t)bh * 65536 + (size_t)d * 1024 + st * 64 + sc);
#pragma unroll
  for (int w = 0; w < 4; w++)
    *(unsigned long long*)(dst + w * 4) = *(unsigned long long*)(us + w * 4);
}

// ---------------------------------------------------------------------------
// Kernel 3: fused scores + rel-pos + gumbel double-softmax + PV.
// One block (8 waves, 512 thr) per (b, h, 32-row l-tile). 1024 blocks.
// vs R8: gumbel rows 0-2 loads hoisted ABOVE Phase A. R2's version of this
// failed only from the (256,5) 48-VGPR squeeze (spill signature); here the
// (512,4) cap is 128 and base usage is 56, so +48 live f32 regs fits.
// The 134 MB gumbel stream now issues across Phase A's compute instead of
// bursting at the A->B barrier, and completes at the barrier's vmcnt drain.
// Spill canary: WRITE_SIZE (expect ~8.6 MB; >20 MB = revert).
// ---------------------------------------------------------------------------
__global__ __launch_bounds__(512, 4) void attn_kernel(
    const _Float16* __restrict__ q_ws, const _Float16* __restrict__ k_ws,
    const _Float16* __restrict__ vT_ws,
    const _Float16* __restrict__ e16,      // [2047][64] fp16
    const unsigned short* __restrict__ gumbel_u,
    const unsigned short* __restrict__ mask,
    float* __restrict__ out)
{
  __shared__ _Float16 St[32 * 1024];  // scores -> probs in place, 65536 B
  __shared__ float Cc[4 * 64 * 8];    // Phase-C partials (r-half 1), 8 KB
  const int tid = threadIdx.x, wave = tid >> 6, lane = tid & 63;
  const int flg = wave_flag(gumbel_u, tid);
  // XCD-locality swizzle: xcd = blk&7; 4 bh per XCD.
  const int blk = blockIdx.x;                  // 0..1023
  const int bh = (blk & 7) * 4 + ((blk >> 3) & 3);
  const int lt = blk >> 5;                     // 0..31
  const int b = bh >> 4, h = bh & 15;
  const int L = lt * 32;
  const _Float16* qp = q_ws + (size_t)bh * 65536;
  const _Float16* kp = k_ws + (size_t)bh * 65536;
  const _Float16* vp = vT_ws + (size_t)bh * 65536;
  const unsigned short* up = gumbel_u + (size_t)bh * 1024 * 1024;
  const float* upf = (const float*)gumbel_u + (size_t)bh * 1024 * 1024;
  const float* maskf = (const float*)mask;
  const int lm = lane & 15, lq = lane >> 4;
  const int rr = wave * 16 + lm;         // this wave's score column in [0,128)

  // Q tile A-fragments: both 16-row groups, held for the whole block
  const f16x8 qa00 = *(const f16x8*)(qp + (L + lm) * 64 + lq * 8);
  const f16x8 qa01 = *(const f16x8*)(qp + (L + lm) * 64 + 32 + lq * 8);
  const f16x8 qa10 = *(const f16x8*)(qp + (L + 16 + lm) * 64 + lq * 8);
  const f16x8 qa11 = *(const f16x8*)(qp + (L + 16 + lm) * 64 + 32 + lq * 8);

  // ---- gumbel load machinery; rows 0-2 issued BEFORE Phase A ----
  const int i0 = wave * 4;
  f32x4 uA[4], uB[4], uC[4];
  auto ldrow = [&](f32x4 (&dst)[4], int i) {
    if (flg) {
      const float* urf = upf + (size_t)(L + i) * 1024 + lane * 4;
#pragma unroll
      for (int c = 0; c < 4; c++)
        dst[c] = __builtin_nontemporal_load((const f32x4*)(urf + c * 256));
    } else {
      const unsigned short* ur = up + (size_t)(L + i) * 1024 + lane * 4;
#pragma unroll
      for (int c = 0; c < 4; c++) {
        union { unsigned long long q; unsigned short u[4]; } ld;
        ld.q = __builtin_nontemporal_load((const unsigned long long*)(ur + c * 256));
        f32x4 v;
#pragma unroll
        for (int j = 0; j < 4; j++) v[j] = bf2f(ld.u[j]);
        dst[c] = v;
      }
    }
  };
  ldrow(uA, i0);
  ldrow(uB, i0 + 1);
  ldrow(uC, i0 + 2);

  // ---- Phase A (no barriers): St = (Q.K^T + Q.E[l-r+1023])/8 + mask ----
#pragma unroll 2
  for (int R = 0; R < 1024; R += 128) {
    const _Float16* krow = kp + (R + rr) * 64;
    const f16x8 kb0 = *(const f16x8*)(krow + lq * 8);
    const f16x8 kb1 = *(const f16x8*)(krow + 32 + lq * 8);
    const int b0 = L - R - wave * 16 + 1008;     // in [0, 2000]
    const int re0 = b0 + lm;                     // <= 2015
    const int re1 = b0 + 16 + lm;                // <= 2031
    int re2 = b0 + 32 + lm;                      // <= 2047: clamp (o=31 unused)
    if (re2 > 2046) re2 = 2046;
    const f16x8 e0a = *(const f16x8*)(e16 + (size_t)re0 * 64 + lq * 8);
    const f16x8 e0b = *(const f16x8*)(e16 + (size_t)re0 * 64 + 32 + lq * 8);
    const f16x8 e1a = *(const f16x8*)(e16 + (size_t)re1 * 64 + lq * 8);
    const f16x8 e1b = *(const f16x8*)(e16 + (size_t)re1 * 64 + 32 + lq * 8);
    const f16x8 e2a = *(const f16x8*)(e16 + (size_t)re2 * 64 + lq * 8);
    const f16x8 e2b = *(const f16x8*)(e16 + (size_t)re2 * 64 + 32 + lq * 8);
    const float mval = flg ? maskf[b * 1024 + R + rr] : bf2f(mask[b * 1024 + R + rr]);

    __builtin_amdgcn_s_setprio(1);
    f32x4 aqk0 = {0.f, 0.f, 0.f, 0.f}, aqk1 = {0.f, 0.f, 0.f, 0.f};
    aqk0 = __builtin_amdgcn_mfma_f32_16x16x32_f16(qa00, kb0, aqk0, 0, 0, 0);
    aqk0 = __builtin_amdgcn_mfma_f32_16x16x32_f16(qa01, kb1, aqk0, 0, 0, 0);
    aqk1 = __builtin_amdgcn_mfma_f32_16x16x32_f16(qa10, kb0, aqk1, 0, 0, 0);
    aqk1 = __builtin_amdgcn_mfma_f32_16x16x32_f16(qa11, kb1, aqk1, 0, 0, 0);
    f32x4 au00 = {0.f, 0.f, 0.f, 0.f}, au01 = {0.f, 0.f, 0.f, 0.f};
    f32x4 au10 = {0.f, 0.f, 0.f, 0.f}, au11 = {0.f, 0.f, 0.f, 0.f};
    au00 = __builtin_amdgcn_mfma_f32_16x16x32_f16(qa00, e0a, au00, 0, 0, 0);
    au00 = __builtin_amdgcn_mfma_f32_16x16x32_f16(qa01, e0b, au00, 0, 0, 0);
    au01 = __builtin_amdgcn_mfma_f32_16x16x32_f16(qa00, e1a, au01, 0, 0, 0);
    au01 = __builtin_amdgcn_mfma_f32_16x16x32_f16(qa01, e1b, au01, 0, 0, 0);
    au10 = __builtin_amdgcn_mfma_f32_16x16x32_f16(qa10, e1a, au10, 0, 0, 0);
    au10 = __builtin_amdgcn_mfma_f32_16x16x32_f16(qa11, e1b, au10, 0, 0, 0);
    au11 = __builtin_amdgcn_mfma_f32_16x16x32_f16(qa10, e2a, au11, 0, 0, 0);
    au11 = __builtin_amdgcn_mfma_f32_16x16x32_f16(qa11, e2b, au11, 0, 0, 0);
    __builtin_amdgcn_s_setprio(0);

#pragma unroll
    for (int rg = 0; rg < 4; rg++) {
      const int o = lq * 4 + rg + 15 - lm;             // [0,30], same both lg
      const int idx = ((lane & 48) | (o & 15)) << 2;   // byte index for bpermute
      const float u00 = __int_as_float(
          __builtin_amdgcn_ds_bpermute(idx, __float_as_int(au00[rg])));
      const float u01 = __int_as_float(
          __builtin_amdgcn_ds_bpermute(idx, __float_as_int(au01[rg])));
      const float uv0 = (o >= 16) ? u01 : u00;
      St[sidx(lq * 4 + rg, R + rr)] = h16((aqk0[rg] + uv0) * 0.125f + mval);
      const float u10 = __int_as_float(
          __builtin_amdgcn_ds_bpermute(idx, __float_as_int(au10[rg])));
      const float u11 = __int_as_float(
          __builtin_amdgcn_ds_bpermute(idx, __float_as_int(au11[rg])));
      const float uv1 = (o >= 16) ? u11 : u10;
      St[sidx(16 + lq * 4 + rg, R + rr)] = h16((aqk1[rg] + uv1) * 0.125f + mval);
    }
  }

  // ---- Phase B: max-free double softmax, 4 rows/wave ----
  auto dorow = [&](const f32x4 (&uv)[4], int i) {
    f16x4 sh[4];
#pragma unroll
    for (int c = 0; c < 4; c++)
      sh[c] = *(const f16x4*)(St + sidx(i, c * 256 + lane * 4));
    float num1[4][4];
    float s1 = 0.f;
#pragma unroll
    for (int c = 0; c < 4; c++)
#pragma unroll
      for (int j = 0; j < 4; j++) {
        const float s = (float)sh[c][j];
        const float nl = neglog(uv[c][j] + 1e-10f) + 1e-10f;
        num1[c][j] = __expf(s) * __builtin_amdgcn_rcpf(nl);
        s1 += num1[c][j];
      }
    s1 = wsum(s1);
    const float is1 = __builtin_amdgcn_rcpf(s1);
    float num2[4][4];
    float s2 = 0.f;
#pragma unroll
    for (int c = 0; c < 4; c++)
#pragma unroll
      for (int j = 0; j < 4; j++) {
        num2[c][j] = __expf((float)sh[c][j] + num1[c][j] * is1);  // TAU_1 = 1
        s2 += num2[c][j];
      }
    s2 = wsum(s2);
    const float is2 = __builtin_amdgcn_rcpf(s2);
#pragma unroll
    for (int c = 0; c < 4; c++) {
      f16x4 pw;
#pragma unroll
      for (int j = 0; j < 4; j++) pw[j] = (_Float16)(num2[c][j] * is2);
      *(f16x4*)(St + sidx(i, c * 256 + lane * 4)) = pw;
    }
  };

  __syncthreads();
  dorow(uA, i0);
  ldrow(uA, i0 + 3);
  dorow(uB, i0 + 1);
  dorow(uC, i0 + 2);
  dorow(uA, i0 + 3);

  // pre-issue first V pair before the barrier
  const int dg = wave & 3, half = wave >> 2;
  const _Float16* vrow = vp + (dg * 16 + lm) * 1024 + half * 512;  // V^T row d
  f16x8 vn0 = *(const f16x8*)(vrow + lq * 8);
  f16x8 vn1 = *(const f16x8*)(vrow + 32 + lq * 8);
  __syncthreads();

  // ---- Phase C: ctx = P.V, r-split by half, one V-frag feeds both lg ----
  f32x4 c00 = {0.f, 0.f, 0.f, 0.f}, c01 = {0.f, 0.f, 0.f, 0.f};
  f32x4 c10 = {0.f, 0.f, 0.f, 0.f}, c11 = {0.f, 0.f, 0.f, 0.f};
#pragma unroll 4
  for (int r0 = 0; r0 < 512; r0 += 64) {
    const f16x8 va0 = vn0, va1 = vn1;
    if (r0 < 448) {
      vn0 = *(const f16x8*)(vrow + r0 + 64 + lq * 8);
      vn1 = *(const f16x8*)(vrow + r0 + 96 + lq * 8);
    }
    const int cb = half * 512 + r0;
    const f16x8 pa00 = *(const f16x8*)(St + sidx(lm, cb + lq * 8));
    const f16x8 pa01 = *(const f16x8*)(St + sidx(lm, cb + 32 + lq * 8));
    const f16x8 pa10 = *(const f16x8*)(St + sidx(16 + lm, cb + lq * 8));
    const f16x8 pa11 = *(const f16x8*)(St + sidx(16 + lm, cb + 32 + lq * 8));
    __builtin_amdgcn_s_setprio(1);
    c00 = __builtin_amdgcn_mfma_f32_16x16x32_f16(pa00, va0, c00, 0, 0, 0);
    c01 = __builtin_amdgcn_mfma_f32_16x16x32_f16(pa01, va1, c01, 0, 0, 0);
    c10 = __builtin_amdgcn_mfma_f32_16x16x32_f16(pa10, va0, c10, 0, 0, 0);
    c11 = __builtin_amdgcn_mfma_f32_16x16x32_f16(pa11, va1, c11, 0, 0, 0);
    __builtin_amdgcn_s_setprio(0);
  }
  f32x4 co0 = c00 + c01, co1 = c10 + c11;

  // combine halves: waves 4-7 park partials; waves 0-3 add + NT-store
  if (wave >= 4) {
    *(f32x4*)(&Cc[(dg * 64 + lane) * 8]) = co0;
    *(f32x4*)(&Cc[(dg * 64 + lane) * 8 + 4]) = co1;
  }
  __syncthreads();
  if (wave < 4) {
    co0 += *(const f32x4*)(&Cc[(dg * 64 + lane) * 8]);
    co1 += *(const f32x4*)(&Cc[(dg * 64 + lane) * 8 + 4]);
#pragma unroll
    for (int rg = 0; rg < 4; rg++) {
      const int i = lq * 4 + rg;
      __builtin_nontemporal_store(co0[rg],
          &out[(size_t)(b * 1024 + L + i) * 1024 + h * 64 + dg * 16 + lm]);
      __builtin_nontemporal_store(co1[rg],
          &out[(size_t)(b * 1024 + L + 16 + i) * 1024 + h * 64 + dg * 16 + lm]);
    }
  }
}

extern "C" void kernel_launch(void* const* d_in, const int* in_sizes, int n_in,
                              void* d_out, int out_size, void* d_ws, size_t ws_size,
                              hipStream_t stream) {
  const unsigned short* hidden = (const unsigned short*)d_in[0];
  const unsigned short* mask   = (const unsigned short*)d_in[1];
  const unsigned short* gum    = (const unsigned short*)d_in[2];
  const unsigned short* Wq     = (const unsigned short*)d_in[3];
  const unsigned short* bq     = (const unsigned short*)d_in[4];
  const unsigned short* Wk     = (const unsigned short*)d_in[5];
  const unsigned short* bk     = (const unsigned short*)d_in[6];
  const unsigned short* Wv     = (const unsigned short*)d_in[7];
  const unsigned short* bv     = (const unsigned short*)d_in[8];
  const unsigned short* de     = (const unsigned short*)d_in[9];

  _Float16* cvt16 = (_Float16*)((char*)d_ws + 256);              // 10 MB (dead after qkv)
  _Float16* q_ws  = cvt16 + (size_t)5 * 1024 * 1024;             // 4 MB
  _Float16* k_ws  = q_ws + (size_t)2 * 1024 * 1024;              // 4 MB
  _Float16* v_ws  = k_ws + (size_t)2 * 1024 * 1024;              // 4 MB
  _Float16* vT_ws = cvt16;             // reuse cvt16[0..2M) after qkv consumed it
  _Float16* e16   = cvt16 + (size_t)2 * 1024 * 1024;  // dead Wq slot, 256 KB
  float* out = (float*)d_out;

  cvt_inputs<<<1280, 256, 0, stream>>>(hidden, Wq, Wk, Wv, gum, cvt16);
  qkv_gemm<<<dim3(16, 24), 512, 0, stream>>>(cvt16, bq, bk, bv, gum,
                                             q_ws, k_ws, v_ws);
  transpose_v_emb<<<dim3(16, 33), 256, 0, stream>>>(v_ws, vT_ws, de, gum, e16);
  attn_kernel<<<1024, 512, 0, stream>>>(q_ws, k_ws, vT_ws, e16, gum, mask, out);
}

// Round 12
// 320.104 us; speedup vs baseline: 1.0452x; 1.0452x over previous
//
#include <hip/hip_runtime.h>
#include <hip/hip_bf16.h>

typedef _Float16 f16x8 __attribute__((ext_vector_type(8)));
typedef _Float16 f16x4 __attribute__((ext_vector_type(4)));
typedef float f32x4 __attribute__((ext_vector_type(4)));
typedef int i32x4 __attribute__((ext_vector_type(4)));

__device__ __forceinline__ float bf2f(unsigned short u) {
  union { unsigned int i; float f; } x; x.i = ((unsigned int)u) << 16; return x.f;
}
// clamp-to-finite fp16 convert: any upstream bug shows finite, not NaN
__device__ __forceinline__ _Float16 h16(float f) {
  return (_Float16)fminf(fmaxf(f, -60000.f), 60000.f);
}

// accurate -log(u): series for u near 1 (1-u exact by Sterbenz there)
__device__ __forceinline__ float neglog(float u) {
  if (u > 0.99f) {
    const float d = 1.0f - u;
    return d + 0.5f * d * d + (1.0f / 3.0f) * d * d * d;
  }
  return -__logf(u);
}

// plain butterfly sum across 64 lanes
__device__ __forceinline__ float wsum(float v) {
#pragma unroll
  for (int off = 1; off < 64; off <<= 1) v += __shfl_xor(v, off, 64);
  return v;
}

// St row-keyed XOR swizzle: element idx ^ ((row&7)<<3) (byte bits 4-6).
__device__ __forceinline__ int sidx(int row, int col) {
  return ((row) * 1024 + (col)) ^ (((row) & 7) << 3);
}

// Per-wave dtype detection. 0 = bf16 inputs, 1 = fp32 inputs.
__device__ __forceinline__ int wave_flag(const unsigned short* __restrict__ g, int tid) {
  const float f = bf2f(g[(tid & 63) * 2]);
  const unsigned long long m = __ballot((f >= 8e-7f) && (f <= 1.0f));
  return (m == ~0ull) ? 0 : 1;
}

// ---------------------------------------------------------------------------
// Kernel 0: convert hidden + Wq/Wk/Wv to fp16 once. Grid-stride, 1280 blocks.
// ---------------------------------------------------------------------------
__global__ __launch_bounds__(256) void cvt_inputs(
    const void* __restrict__ h, const void* __restrict__ wq,
    const void* __restrict__ wk, const void* __restrict__ wv,
    const unsigned short* __restrict__ gum, _Float16* __restrict__ dst)
{
  const int flg = wave_flag(gum, threadIdx.x);
  for (int c = blockIdx.x * 256 + threadIdx.x; c < 1310720; c += 1280 * 256) {
    const int c4 = c * 4;
    const void* src;
    int si;
    if (c4 < 2097152) { src = h; si = c4; }
    else {
      const int w = (c4 - 2097152) >> 20;        // 0,1,2
      si = (c4 - 2097152) & 1048575;
      src = (w == 0) ? wq : (w == 1) ? wk : wv;
    }
    f16x4 o;
    if (flg) {
      f32x4 v = __builtin_nontemporal_load((const f32x4*)((const float*)src + si));
#pragma unroll
      for (int j = 0; j < 4; j++) o[j] = h16(v[j]);
    } else {
      unsigned long long q = __builtin_nontemporal_load(
          (const unsigned long long*)((const unsigned short*)src + si));
      union { unsigned long long q; unsigned short u[4]; } ld; ld.q = q;
#pragma unroll
      for (int j = 0; j < 4; j++) o[j] = h16(bf2f(ld.u[j]));
    }
    *(f16x4*)(dst + c4) = o;
  }
}

// ---------------------------------------------------------------------------
// Kernel 1: QKV projection on pre-converted fp16. NT gemm 2048 x 3072 x 1024.
// 64x128 tiles, BK=64, 768 blocks (3/CU), reg-staged next-chunk prefetch.
// (R7-verified configuration — best measured total.)
// ---------------------------------------------------------------------------
__global__ __launch_bounds__(256, 3) void qkv_gemm(
    const _Float16* __restrict__ cvt,   // [hid | Wq | Wk | Wv]
    const unsigned short* __restrict__ bq, const unsigned short* __restrict__ bk,
    const unsigned short* __restrict__ bv,
    const unsigned short* __restrict__ gum,
    _Float16* __restrict__ q_ws, _Float16* __restrict__ k_ws,
    _Float16* __restrict__ v_ws)
{
  __shared__ _Float16 At[64][72];   // 64 x 64 fp16, +8 pad
  __shared__ _Float16 Bt[128][72];  // 128 x 64 fp16, +8 pad
  const int flg = wave_flag(gum, threadIdx.x);
  const int tn = blockIdx.x;        // 32 M-tiles of 64 rows
  const int to = blockIdx.y;        // 24 N-tiles of 128 cols over [q|k|v]
  const int mat = to >> 3;          // 0=q 1=k 2=v
  const int o0 = (to & 7) * 128;
  const _Float16* hid16 = cvt;
  const _Float16* W16 = cvt + (size_t)(2 * 1024 * 1024) + (size_t)mat * 1024 * 1024;
  const unsigned short* bias = (mat == 0) ? bq : (mat == 1) ? bk : bv;
  const float* biasf = (const float*)bias;
  const int tid = threadIdx.x;
  const int lane = tid & 63, wave = tid >> 6;
  const int wm = (wave >> 1) * 32, wn = (wave & 1) * 64;  // 2x2 quadrants 32x64
  const int lm = lane & 15, lq = lane >> 4;
  f32x4 acc[2][4] = {};

  // per-thread staging addresses (row/chunk fixed; kc varies)
  const int ra0 = tid >> 3, ca = tid & 7;          // A rows: ra0, ra0+32
  const int rb0 = tid >> 3, cb = tid & 7;          // B rows: rb0 + 32*i
  i32x4 rA[2], rB[4];
  auto ldglobal = [&](int kc) {
#pragma unroll
    for (int i = 0; i < 2; i++)
      rA[i] = *(const i32x4*)(hid16 + (size_t)(tn * 64 + ra0 + i * 32) * 1024 + kc + ca * 8);
#pragma unroll
    for (int i = 0; i < 4; i++)
      rB[i] = *(const i32x4*)(W16 + (size_t)(o0 + rb0 + i * 32) * 1024 + kc + cb * 8);
  };

  ldglobal(0);
  for (int kc = 0; kc < 1024; kc += 64) {
    __syncthreads();   // previous chunk's frag reads complete
#pragma unroll
    for (int i = 0; i < 2; i++)
      *(i32x4*)(&At[ra0 + i * 32][ca * 8]) = rA[i];
#pragma unroll
    for (int i = 0; i < 4; i++)
      *(i32x4*)(&Bt[rb0 + i * 32][cb * 8]) = rB[i];
    __syncthreads();
    if (kc < 960) ldglobal(kc + 64);   // overlap next loads with MFMAs below

    f16x8 af[2][2], bfr[4][2];
#pragma unroll
    for (int mt = 0; mt < 2; mt++)
#pragma unroll
      for (int k2 = 0; k2 < 2; k2++)
        af[mt][k2] = *(const f16x8*)(&At[wm + mt * 16 + lm][k2 * 32 + lq * 8]);
#pragma unroll
    for (int nt = 0; nt < 4; nt++)
#pragma unroll
      for (int k2 = 0; k2 < 2; k2++)
        bfr[nt][k2] = *(const f16x8*)(&Bt[wn + nt * 16 + lm][k2 * 32 + lq * 8]);
#pragma unroll
    for (int mt = 0; mt < 2; mt++)
#pragma unroll
      for (int nt = 0; nt < 4; nt++)
#pragma unroll
        for (int k2 = 0; k2 < 2; k2++)
          acc[mt][nt] = __builtin_amdgcn_mfma_f32_16x16x32_f16(
              af[mt][k2], bfr[nt][k2], acc[mt][nt], 0, 0, 0);
  }

  // epilogue: C/D layout col=lane&15, row=quad*4+reg
  _Float16* dst = (mat == 0) ? q_ws : (mat == 1) ? k_ws : v_ws;
#pragma unroll
  for (int nt = 0; nt < 4; nt++) {
    const int ol = o0 + wn + nt * 16 + lm;
    const float bias_v = flg ? biasf[ol] : bf2f(bias[ol]);
    const int hh = ol >> 6, dd = ol & 63;
#pragma unroll
    for (int mt = 0; mt < 2; mt++) {
#pragma unroll
      for (int rg = 0; rg < 4; rg++) {
        const int n = tn * 64 + wm + mt * 16 + lq * 4 + rg;  // b*1024+s
        const int b = n >> 10, s = n & 1023;
        dst[((size_t)(b * 16 + hh) * 1024 + s) * 64 + dd] = h16(acc[mt][nt][rg] + bias_v);
      }
    }
  }
}

// ---------------------------------------------------------------------------
// Kernel 2: transpose v [bh][s][64] -> vT [bh][64][s] via LDS 64x64 tiles,
// plus (grid y==32) dist_emb -> fp16 conversion.
// ---------------------------------------------------------------------------
__global__ __launch_bounds__(256) void transpose_v_emb(
    const _Float16* __restrict__ v_ws, _Float16* __restrict__ vT_ws,
    const void* __restrict__ de, const unsigned short* __restrict__ gum,
    _Float16* __restrict__ e16)
{
  __shared__ unsigned short Tt[64 * 66];
  const int tid = threadIdx.x;

  if (blockIdx.y == 32) {
    // dist_emb conversion: 2047*64 = 131008 halves = 32752 vec4 chunks
    const int flg = wave_flag(gum, tid);
    for (int c = blockIdx.x * 256 + tid; c < 32752; c += 16 * 256) {
      const int idx = c * 4;
      f16x4 o;
      if (flg) {
        f32x4 v = *(const f32x4*)((const float*)de + idx);
#pragma unroll
        for (int j = 0; j < 4; j++) o[j] = h16(v[j]);
      } else {
        union { unsigned long long q; unsigned short u[4]; } ld;
        ld.q = *(const unsigned long long*)((const unsigned short*)de + idx);
#pragma unroll
        for (int j = 0; j < 4; j++) o[j] = h16(bf2f(ld.u[j]));
      }
      *(f16x4*)(e16 + idx) = o;
    }
    return;
  }

  const int st = blockIdx.x;   // 16 s-tiles
  const int bh = blockIdx.y;   // 32
  const unsigned short* src = (const unsigned short*)(v_ws + (size_t)bh * 65536);
#pragma unroll
  for (int i = 0; i < 2; i++) {
    const int cid = i * 256 + tid;
    const int r = cid >> 3, c8 = cid & 7;   // row in tile, 8-half chunk
    union { i32x4 v; unsigned int w[4]; } ld;
    ld.v = *(const i32x4*)(src + (size_t)(st * 64 + r) * 64 + c8 * 8);
#pragma unroll
    for (int w = 0; w < 4; w++)
      *(unsigned int*)(&Tt[r * 66 + c8 * 8 + w * 2]) = ld.w[w];
  }
  __syncthreads();
  const int d = tid >> 2, sc = (tid & 3) * 16;
  unsigned short us[16];
#pragma unroll
  for (int j = 0; j < 16; j++) us[j] = Tt[(sc + j) * 66 + d];
  unsigned short* dst = (unsigned short*)(vT_ws + (size_t)bh * 65536 + (size_t)d * 1024 + st * 64 + sc);
#pragma unroll
  for (int w = 0; w < 4; w++)
    *(unsigned long long*)(dst + w * 4) = *(unsigned long long*)(us + w * 4);
}

// ---------------------------------------------------------------------------
// Kernel 3: fused scores + rel-pos + gumbel double-softmax + PV.
// One block (8 waves, 512 thr) per (b, h, 32-row l-tile). 1024 blocks.
// R6 traffic structure + R7 setprio. Gumbel prefetch at R4-proven placement
// (AFTER Phase A, before the barrier) — hoisting above Phase A spills
// (falsified twice: R2 and R11, both with WRITE_SIZE canary firing).
// ---------------------------------------------------------------------------
__global__ __launch_bounds__(512, 4) void attn_kernel(
    const _Float16* __restrict__ q_ws, const _Float16* __restrict__ k_ws,
    const _Float16* __restrict__ vT_ws,
    const _Float16* __restrict__ e16,      // [2047][64] fp16
    const unsigned short* __restrict__ gumbel_u,
    const unsigned short* __restrict__ mask,
    float* __restrict__ out)
{
  __shared__ _Float16 St[32 * 1024];  // scores -> probs in place, 65536 B
  __shared__ float Cc[4 * 64 * 8];    // Phase-C partials (r-half 1), 8 KB
  const int tid = threadIdx.x, wave = tid >> 6, lane = tid & 63;
  const int flg = wave_flag(gumbel_u, tid);
  // XCD-locality swizzle: xcd = blk&7; 4 bh per XCD.
  const int blk = blockIdx.x;                  // 0..1023
  const int bh = (blk & 7) * 4 + ((blk >> 3) & 3);
  const int lt = blk >> 5;                     // 0..31
  const int b = bh >> 4, h = bh & 15;
  const int L = lt * 32;
  const _Float16* qp = q_ws + (size_t)bh * 65536;
  const _Float16* kp = k_ws + (size_t)bh * 65536;
  const _Float16* vp = vT_ws + (size_t)bh * 65536;
  const unsigned short* up = gumbel_u + (size_t)bh * 1024 * 1024;
  const float* upf = (const float*)gumbel_u + (size_t)bh * 1024 * 1024;
  const float* maskf = (const float*)mask;
  const int lm = lane & 15, lq = lane >> 4;
  const int rr = wave * 16 + lm;         // this wave's score column in [0,128)

  // Q tile A-fragments: both 16-row groups, held for the whole block
  const f16x8 qa00 = *(const f16x8*)(qp + (L + lm) * 64 + lq * 8);
  const f16x8 qa01 = *(const f16x8*)(qp + (L + lm) * 64 + 32 + lq * 8);
  const f16x8 qa10 = *(const f16x8*)(qp + (L + 16 + lm) * 64 + lq * 8);
  const f16x8 qa11 = *(const f16x8*)(qp + (L + 16 + lm) * 64 + 32 + lq * 8);

  // ---- Phase A (no barriers): St = (Q.K^T + Q.E[l-r+1023])/8 + mask ----
#pragma unroll 2
  for (int R = 0; R < 1024; R += 128) {
    const _Float16* krow = kp + (R + rr) * 64;
    const f16x8 kb0 = *(const f16x8*)(krow + lq * 8);
    const f16x8 kb1 = *(const f16x8*)(krow + 32 + lq * 8);
    const int b0 = L - R - wave * 16 + 1008;     // in [0, 2000]
    const int re0 = b0 + lm;                     // <= 2015
    const int re1 = b0 + 16 + lm;                // <= 2031
    int re2 = b0 + 32 + lm;                      // <= 2047: clamp (o=31 unused)
    if (re2 > 2046) re2 = 2046;
    const f16x8 e0a = *(const f16x8*)(e16 + (size_t)re0 * 64 + lq * 8);
    const f16x8 e0b = *(const f16x8*)(e16 + (size_t)re0 * 64 + 32 + lq * 8);
    const f16x8 e1a = *(const f16x8*)(e16 + (size_t)re1 * 64 + lq * 8);
    const f16x8 e1b = *(const f16x8*)(e16 + (size_t)re1 * 64 + 32 + lq * 8);
    const f16x8 e2a = *(const f16x8*)(e16 + (size_t)re2 * 64 + lq * 8);
    const f16x8 e2b = *(const f16x8*)(e16 + (size_t)re2 * 64 + 32 + lq * 8);
    const float mval = flg ? maskf[b * 1024 + R + rr] : bf2f(mask[b * 1024 + R + rr]);

    __builtin_amdgcn_s_setprio(1);
    f32x4 aqk0 = {0.f, 0.f, 0.f, 0.f}, aqk1 = {0.f, 0.f, 0.f, 0.f};
    aqk0 = __builtin_amdgcn_mfma_f32_16x16x32_f16(qa00, kb0, aqk0, 0, 0, 0);
    aqk0 = __builtin_amdgcn_mfma_f32_16x16x32_f16(qa01, kb1, aqk0, 0, 0, 0);
    aqk1 = __builtin_amdgcn_mfma_f32_16x16x32_f16(qa10, kb0, aqk1, 0, 0, 0);
    aqk1 = __builtin_amdgcn_mfma_f32_16x16x32_f16(qa11, kb1, aqk1, 0, 0, 0);
    f32x4 au00 = {0.f, 0.f, 0.f, 0.f}, au01 = {0.f, 0.f, 0.f, 0.f};
    f32x4 au10 = {0.f, 0.f, 0.f, 0.f}, au11 = {0.f, 0.f, 0.f, 0.f};
    au00 = __builtin_amdgcn_mfma_f32_16x16x32_f16(qa00, e0a, au00, 0, 0, 0);
    au00 = __builtin_amdgcn_mfma_f32_16x16x32_f16(qa01, e0b, au00, 0, 0, 0);
    au01 = __builtin_amdgcn_mfma_f32_16x16x32_f16(qa00, e1a, au01, 0, 0, 0);
    au01 = __builtin_amdgcn_mfma_f32_16x16x32_f16(qa01, e1b, au01, 0, 0, 0);
    au10 = __builtin_amdgcn_mfma_f32_16x16x32_f16(qa10, e1a, au10, 0, 0, 0);
    au10 = __builtin_amdgcn_mfma_f32_16x16x32_f16(qa11, e1b, au10, 0, 0, 0);
    au11 = __builtin_amdgcn_mfma_f32_16x16x32_f16(qa10, e2a, au11, 0, 0, 0);
    au11 = __builtin_amdgcn_mfma_f32_16x16x32_f16(qa11, e2b, au11, 0, 0, 0);
    __builtin_amdgcn_s_setprio(0);

#pragma unroll
    for (int rg = 0; rg < 4; rg++) {
      const int o = lq * 4 + rg + 15 - lm;             // [0,30], same both lg
      const int idx = ((lane & 48) | (o & 15)) << 2;   // byte index for bpermute
      const float u00 = __int_as_float(
          __builtin_amdgcn_ds_bpermute(idx, __float_as_int(au00[rg])));
      const float u01 = __int_as_float(
          __builtin_amdgcn_ds_bpermute(idx, __float_as_int(au01[rg])));
      const float uv0 = (o >= 16) ? u01 : u00;
      St[sidx(lq * 4 + rg, R + rr)] = h16((aqk0[rg] + uv0) * 0.125f + mval);
      const float u10 = __int_as_float(
          __builtin_amdgcn_ds_bpermute(idx, __float_as_int(au10[rg])));
      const float u11 = __int_as_float(
          __builtin_amdgcn_ds_bpermute(idx, __float_as_int(au11[rg])));
      const float uv1 = (o >= 16) ? u11 : u10;
      St[sidx(16 + lq * 4 + rg, R + rr)] = h16((aqk1[rg] + uv1) * 0.125f + mval);
    }
  }

  // ---- Phase B: max-free double softmax, 4 rows/wave, 3-deep prefetch ----
  const int i0 = wave * 4;
  f32x4 uA[4], uB[4], uC[4];
  auto ldrow = [&](f32x4 (&dst)[4], int i) {
    if (flg) {
      const float* urf = upf + (size_t)(L + i) * 1024 + lane * 4;
#pragma unroll
      for (int c = 0; c < 4; c++)
        dst[c] = __builtin_nontemporal_load((const f32x4*)(urf + c * 256));
    } else {
      const unsigned short* ur = up + (size_t)(L + i) * 1024 + lane * 4;
#pragma unroll
      for (int c = 0; c < 4; c++) {
        union { unsigned long long q; unsigned short u[4]; } ld;
        ld.q = __builtin_nontemporal_load((const unsigned long long*)(ur + c * 256));
        f32x4 v;
#pragma unroll
        for (int j = 0; j < 4; j++) v[j] = bf2f(ld.u[j]);
        dst[c] = v;
      }
    }
  };
  auto dorow = [&](const f32x4 (&uv)[4], int i) {
    f16x4 sh[4];
#pragma unroll
    for (int c = 0; c < 4; c++)
      sh[c] = *(const f16x4*)(St + sidx(i, c * 256 + lane * 4));
    float num1[4][4];
    float s1 = 0.f;
#pragma unroll
    for (int c = 0; c < 4; c++)
#pragma unroll
      for (int j = 0; j < 4; j++) {
        const float s = (float)sh[c][j];
        const float nl = neglog(uv[c][j] + 1e-10f) + 1e-10f;
        num1[c][j] = __expf(s) * __builtin_amdgcn_rcpf(nl);
        s1 += num1[c][j];
      }
    s1 = wsum(s1);
    const float is1 = __builtin_amdgcn_rcpf(s1);
    float num2[4][4];
    float s2 = 0.f;
#pragma unroll
    for (int c = 0; c < 4; c++)
#pragma unroll
      for (int j = 0; j < 4; j++) {
        num2[c][j] = __expf((float)sh[c][j] + num1[c][j] * is1);  // TAU_1 = 1
        s2 += num2[c][j];
      }
    s2 = wsum(s2);
    const float is2 = __builtin_amdgcn_rcpf(s2);
#pragma unroll
    for (int c = 0; c < 4; c++) {
      f16x4 pw;
#pragma unroll
      for (int j = 0; j < 4; j++) pw[j] = (_Float16)(num2[c][j] * is2);
      *(f16x4*)(St + sidx(i, c * 256 + lane * 4)) = pw;
    }
  };

  // issue 3 rows right before the barrier (R4-proven placement/depth)
  ldrow(uA, i0);
  ldrow(uB, i0 + 1);
  ldrow(uC, i0 + 2);
  __syncthreads();
  dorow(uA, i0);
  ldrow(uA, i0 + 3);
  dorow(uB, i0 + 1);
  dorow(uC, i0 + 2);
  dorow(uA, i0 + 3);

  // pre-issue first V pair before the barrier
  const int dg = wave & 3, half = wave >> 2;
  const _Float16* vrow = vp + (dg * 16 + lm) * 1024 + half * 512;  // V^T row d
  f16x8 vn0 = *(const f16x8*)(vrow + lq * 8);
  f16x8 vn1 = *(const f16x8*)(vrow + 32 + lq * 8);
  __syncthreads();

  // ---- Phase C: ctx = P.V, r-split by half, one V-frag feeds both lg ----
  f32x4 c00 = {0.f, 0.f, 0.f, 0.f}, c01 = {0.f, 0.f, 0.f, 0.f};
  f32x4 c10 = {0.f, 0.f, 0.f, 0.f}, c11 = {0.f, 0.f, 0.f, 0.f};
#pragma unroll 4
  for (int r0 = 0; r0 < 512; r0 += 64) {
    const f16x8 va0 = vn0, va1 = vn1;
    if (r0 < 448) {
      vn0 = *(const f16x8*)(vrow + r0 + 64 + lq * 8);
      vn1 = *(const f16x8*)(vrow + r0 + 96 + lq * 8);
    }
    const int cb = half * 512 + r0;
    const f16x8 pa00 = *(const f16x8*)(St + sidx(lm, cb + lq * 8));
    const f16x8 pa01 = *(const f16x8*)(St + sidx(lm, cb + 32 + lq * 8));
    const f16x8 pa10 = *(const f16x8*)(St + sidx(16 + lm, cb + lq * 8));
    const f16x8 pa11 = *(const f16x8*)(St + sidx(16 + lm, cb + 32 + lq * 8));
    __builtin_amdgcn_s_setprio(1);
    c00 = __builtin_amdgcn_mfma_f32_16x16x32_f16(pa00, va0, c00, 0, 0, 0);
    c01 = __builtin_amdgcn_mfma_f32_16x16x32_f16(pa01, va1, c01, 0, 0, 0);
    c10 = __builtin_amdgcn_mfma_f32_16x16x32_f16(pa10, va0, c10, 0, 0, 0);
    c11 = __builtin_amdgcn_mfma_f32_16x16x32_f16(pa11, va1, c11, 0, 0, 0);
    __builtin_amdgcn_s_setprio(0);
  }
  f32x4 co0 = c00 + c01, co1 = c10 + c11;

  // combine halves: waves 4-7 park partials; waves 0-3 add + NT-store
  if (wave >= 4) {
    *(f32x4*)(&Cc[(dg * 64 + lane) * 8]) = co0;
    *(f32x4*)(&Cc[(dg * 64 + lane) * 8 + 4]) = co1;
  }
  __syncthreads();
  if (wave < 4) {
    co0 += *(const f32x4*)(&Cc[(dg * 64 + lane) * 8]);
    co1 += *(const f32x4*)(&Cc[(dg * 64 + lane) * 8 + 4]);
#pragma unroll
    for (int rg = 0; rg < 4; rg++) {
      const int i = lq * 4 + rg;
      __builtin_nontemporal_store(co0[rg],
          &out[(size_t)(b * 1024 + L + i) * 1024 + h * 64 + dg * 16 + lm]);
      __builtin_nontemporal_store(co1[rg],
          &out[(size_t)(b * 1024 + L + 16 + i) * 1024 + h * 64 + dg * 16 + lm]);
    }
  }
}

extern "C" void kernel_launch(void* const* d_in, const int* in_sizes, int n_in,
                              void* d_out, int out_size, void* d_ws, size_t ws_size,
                              hipStream_t stream) {
  const unsigned short* hidden = (const unsigned short*)d_in[0];
  const unsigned short* mask   = (const unsigned short*)d_in[1];
  const unsigned short* gum    = (const unsigned short*)d_in[2];
  const unsigned short* Wq     = (const unsigned short*)d_in[3];
  const unsigned short* bq     = (const unsigned short*)d_in[4];
  const unsigned short* Wk     = (const unsigned short*)d_in[5];
  const unsigned short* bk     = (const unsigned short*)d_in[6];
  const unsigned short* Wv     = (const unsigned short*)d_in[7];
  const unsigned short* bv     = (const unsigned short*)d_in[8];
  const unsigned short* de     = (const unsigned short*)d_in[9];

  _Float16* cvt16 = (_Float16*)((char*)d_ws + 256);              // 10 MB (dead after qkv)
  _Float16* q_ws  = cvt16 + (size_t)5 * 1024 * 1024;             // 4 MB
  _Float16* k_ws  = q_ws + (size_t)2 * 1024 * 1024;              // 4 MB
  _Float16* v_ws  = k_ws + (size_t)2 * 1024 * 1024;              // 4 MB
  _Float16* vT_ws = cvt16;             // reuse cvt16[0..2M) after qkv consumed it
  _Float16* e16   = cvt16 + (size_t)2 * 1024 * 1024;  // dead Wq slot, 256 KB
  float* out = (float*)d_out;

  cvt_inputs<<<1280, 256, 0, stream>>>(hidden, Wq, Wk, Wv, gum, cvt16);
  qkv_gemm<<<dim3(32, 24), 256, 0, stream>>>(cvt16, bq, bk, bv, gum,
                                             q_ws, k_ws, v_ws);
  transpose_v_emb<<<dim3(16, 33), 256, 0, stream>>>(v_ws, vT_ws, de, gum, e16);
  attn_kernel<<<1024, 512, 0, stream>>>(q_ws, k_ws, vT_ws, e16, gum, mask, out);
}